// Round 9
// baseline (213.079 us; speedup 1.0000x reference)
//
#include <hip/hip_runtime.h>
#include <hip/hip_bf16.h>
#include <stdint.h>

#define BATCH 8192
#define GROWS 8448          // 8192 + per-expert thin padding (<=31/expert) margin
#define DIN   2048
#define DOUT  2048
#define NEXP  8
#define BM    128
#define BN    256
#define BK    32
#define BUFSZ 24576         // per K-tile buffer: A 8K + B 16K
#define BOFF  8192          // B region offset within buffer

typedef __attribute__((ext_vector_type(4))) float fx4;
typedef __attribute__((ext_vector_type(8))) short sx8;

__device__ __forceinline__ short f2b(float x){
  unsigned u = __float_as_uint(x);
  u = u + 0x7FFFu + ((u >> 16) & 1u);   // round-to-nearest-even
  return (short)(u >> 16);
}

__device__ __forceinline__ void gload16(const void* g, void* l){
  __builtin_amdgcn_global_load_lds(
      (const __attribute__((address_space(1))) unsigned int*)g,
      (__attribute__((address_space(3))) unsigned int*)l, 16, 0, 0);
}
__device__ __forceinline__ void gload4(const void* g, void* l){
  __builtin_amdgcn_global_load_lds(
      (const __attribute__((address_space(1))) unsigned int*)g,
      (__attribute__((address_space(3))) unsigned int*)l, 4, 0, 0);
}

// ---- K1: hetero {transw (8192 blocks)} || {count+LUT build (block 8192)} ----
// meta: [0..7] scatter cursors, [8] nfull items, [9] nthin items, [10] thin ctr,
//       [16..79] full-slot expert, [80..143] full-slot row base,
//       [144..175] thin-slot expert, [176..207] thin-slot row base
__global__ void k1_kernel(const float* __restrict__ W, short* __restrict__ Wt,
                          const int* __restrict__ actions, int* __restrict__ perm,
                          int* __restrict__ meta){
  __shared__ float tile[64][69];
  int t = threadIdx.x;   // 256
  if (blockIdx.x == 8192){
    int* cnt = (int*)tile;
    if (t < NEXP) cnt[t] = 0;
    for (int i = t; i < GROWS; i += 256) perm[i] = -1;
    __syncthreads();
    for (int i = t; i < BATCH; i += 256) atomicAdd(&cnt[actions[i]], 1);
    __syncthreads();
    if (t == 0){
      int base = 0, fs = 0, ts = 0;
      for (int e = 0; e < NEXP; ++e){
        meta[e] = base;                       // scatter cursor = segment start
        int f = cnt[e] >> 7, rem = cnt[e] & 127;
        for (int q = 0; q < f; ++q){ meta[16 + fs] = e; meta[80 + fs] = base; base += 128; ++fs; }
        int th = (rem + 31) >> 5;
        for (int q = 0; q < th; ++q){ meta[144 + ts] = e; meta[176 + ts] = base; base += 32; ++ts; }
      }
      meta[8] = fs * 8; meta[9] = ts * 8; meta[10] = 0;
    }
    return;
  }
  // transw: W[e][k][n] f32 -> Wt[e][n][k] bf16 (64x64 tiles)
  int id = blockIdx.x;
  int e  = id >> 10;
  int r2 = id & 1023;
  int k0 = (r2 >> 5) << 6;
  int n0 = (r2 & 31) << 6;
  const float* Wp = W + (size_t)e * DIN * DOUT + (size_t)k0 * DOUT + n0;
#pragma unroll
  for (int it = 0; it < 4; ++it){
    int r = it * 16 + (t >> 4);
    int c = (t & 15) * 4;
    fx4 v = *(const fx4*)(Wp + (size_t)r * DOUT + c);
    tile[r][c] = v.x; tile[r][c+1] = v.y; tile[r][c+2] = v.z; tile[r][c+3] = v.w;
  }
  __syncthreads();
  int n  = t >> 2;
  int kc = (t & 3) * 16;
  short vv[16];
#pragma unroll
  for (int j = 0; j < 16; ++j) vv[j] = f2b(tile[kc + j][n]);
  short* dst = Wt + (size_t)e * DOUT * DIN + (size_t)(n0 + n) * DIN + k0 + kc;
  *(sx8*)dst       = *(const sx8*)vv;
  *(sx8*)(dst + 8) = *(const sx8*)(vv + 8);
}

// ---- K2: scatter perm + metadata tail ----
__global__ void prep_scatter(const int* __restrict__ actions, const int* __restrict__ mxs,
                             int* __restrict__ perm, int* __restrict__ meta,
                             float* __restrict__ out){
  int i = blockIdx.x * 256 + threadIdx.x;
  if (i < BATCH){
    int e = actions[i];
    int p = atomicAdd(&meta[e], 1);
    perm[p] = i;
    out[(size_t)BATCH * DOUT + i]         = (float)mxs[i];
    out[(size_t)BATCH * DOUT + BATCH + i] = (float)actions[i];
  }
}

// ---- K3: gather + convert: xp[i][k] = bf16(xs[perm[i]][k]); pad rows -> 0 ----
__global__ void gatherx_kernel(const float* __restrict__ xs, const int* __restrict__ perm,
                               short* __restrict__ xp){
  int i = blockIdx.x;
  int t = threadIdx.x;
  short v[8];
  int p = perm[i];
  if (p >= 0){
    const fx4* src = (const fx4*)(xs + (size_t)p * DIN + t * 8);
    fx4 a = src[0], b2 = src[1];
    v[0]=f2b(a.x); v[1]=f2b(a.y); v[2]=f2b(a.z); v[3]=f2b(a.w);
    v[4]=f2b(b2.x); v[5]=f2b(b2.y); v[6]=f2b(b2.z); v[7]=f2b(b2.w);
  } else {
#pragma unroll
    for (int j = 0; j < 8; ++j) v[j] = 0;
  }
  *(sx8*)(xp + (size_t)i * DIN + t * 8) = *(const sx8*)v;
}

// ---- K4: grouped GEMM: static full slots (R4-proven) + work-steal 32-row thin slots ----
__global__ __launch_bounds__(512, 4)
void moe_gemm_kernel(const short* __restrict__ xp, const short* __restrict__ Wt,
                     const float* __restrict__ bias, const int* __restrict__ perm,
                     int* __restrict__ meta, float* __restrict__ out){
  __shared__ char lds[3 * BUFSZ];   // 72 KB -> 2 blocks/CU
  __shared__ int s_item;

  int t    = threadIdx.x;
  int wid  = t >> 6;
  int l    = t & 63;
  int wm   = wid & 1;               // 2 wave rows (full path)
  int wn   = wid >> 1;              // 4 wave cols (both paths)
  int lrow = l & 15;
  int lk   = l >> 4;

  // full-path staging geometry
  int srow = ((t >> 3) << 1) | ((t >> 2) & 1);
  int schk = (t & 3) ^ ((t >> 3) & 3);
  int ldst = t * 16;
  int arow = wm * 64 + lrow;
  int aline = arow >> 1;
  int addrA = aline * 128 + (arow & 1) * 64 + ((lk ^ (aline & 3)) << 4);
  int brow = wn * 64 + lrow;
  int bline = brow >> 1;
  int addrB = BOFF + bline * 128 + (brow & 1) * 64 + ((lk ^ (bline & 3)) << 4);

  int nfull = meta[8], nthin = meta[9];
  int F = blockIdx.x;

  // ================= FULL 128x256 item (static, XCD-aligned: nb = F&7) =================
  if (F < nfull){
    int slot = F >> 3, nb = F & 7;
    int e      = meta[16 + slot];
    int m_base = meta[80 + slot];
    int n0     = nb * BN;

    const char* ag  = (const char*)xp + ((size_t)(m_base + srow) * DIN + schk * 8) * 2;
    const char* bg0 = (const char*)Wt + (((size_t)e * DOUT + n0 + srow) * DIN + schk * 8) * 2;
    const char* bg1 = bg0 + (size_t)128 * DIN * 2;

#define STAGE(kt, BASE) do{ \
    gload16(ag  + (size_t)(kt) * 64, lds + (BASE) + ldst); \
    gload16(bg0 + (size_t)(kt) * 64, lds + (BASE) + BOFF + ldst); \
    gload16(bg1 + (size_t)(kt) * 64, lds + (BASE) + BOFF + 8192 + ldst); \
  }while(0)

    fx4 acc[4][4];
#pragma unroll
    for (int m = 0; m < 4; ++m)
#pragma unroll
      for (int n = 0; n < 4; ++n)
        acc[m][n] = (fx4){0.f, 0.f, 0.f, 0.f};

    float bcol[4];
#pragma unroll
    for (int n = 0; n < 4; ++n)
      bcol[n] = bias[(size_t)e * DOUT + n0 + wn * 64 + n * 16 + lrow];

#define KSTEP(CB, SB, DOSTG, kt) do{ \
    sx8 af[4], bf[4]; \
    _Pragma("unroll") for (int m = 0; m < 4; ++m) \
      af[m] = *(const sx8*)(lds + (CB) + addrA + m * 1024); \
    _Pragma("unroll") for (int n = 0; n < 4; ++n) \
      bf[n] = *(const sx8*)(lds + (CB) + addrB + n * 1024); \
    if (DOSTG) STAGE((kt) + 2, SB); \
    __builtin_amdgcn_s_setprio(1); \
    _Pragma("unroll") for (int m = 0; m < 4; ++m) \
    _Pragma("unroll") for (int n = 0; n < 4; ++n) \
      acc[m][n] = __builtin_amdgcn_mfma_f32_16x16x32_bf16(af[m], bf[n], acc[m][n], 0, 0, 0); \
    __builtin_amdgcn_s_setprio(0); \
    if (DOSTG) asm volatile("s_waitcnt vmcnt(3)" ::: "memory"); \
    else       asm volatile("s_waitcnt vmcnt(0)" ::: "memory"); \
    __builtin_amdgcn_s_barrier(); \
    asm volatile("" ::: "memory"); \
  }while(0)

    STAGE(0, 0);
    STAGE(1, BUFSZ);
    asm volatile("s_waitcnt vmcnt(3)" ::: "memory");
    __builtin_amdgcn_s_barrier();
    asm volatile("" ::: "memory");

    for (int kt = 0; kt < 60; kt += 3){
      KSTEP(0,         2*BUFSZ, 1, kt);
      KSTEP(BUFSZ,     0,       1, kt + 1);
      KSTEP(2*BUFSZ,   BUFSZ,   1, kt + 2);
    }
    KSTEP(0,       2*BUFSZ, 1, 60);
    KSTEP(BUFSZ,   0,       1, 61);
    KSTEP(2*BUFSZ, 0,       0, 62);
    {
      sx8 af[4], bf[4];
#pragma unroll
      for (int m = 0; m < 4; ++m) af[m] = *(const sx8*)(lds + addrA + m * 1024);
#pragma unroll
      for (int n = 0; n < 4; ++n) bf[n] = *(const sx8*)(lds + addrB + n * 1024);
#pragma unroll
      for (int m = 0; m < 4; ++m)
#pragma unroll
        for (int n = 0; n < 4; ++n)
          acc[m][n] = __builtin_amdgcn_mfma_f32_16x16x32_bf16(af[m], bf[n], acc[m][n], 0, 0, 0);
    }

#pragma unroll
    for (int m = 0; m < 4; ++m){
      int rb = wm * 64 + m * 16 + lk * 4;
      int prow[4];
#pragma unroll
      for (int q = 0; q < 4; ++q)
        prow[q] = perm[m_base + rb + q];
#pragma unroll
      for (int n = 0; n < 4; ++n){
        int col = n0 + wn * 64 + n * 16 + lrow;
        fx4 v = acc[m][n];
#pragma unroll
        for (int q = 0; q < 4; ++q)
          if (prow[q] >= 0)
            out[(size_t)prow[q] * DOUT + col] = v[q] + bcol[n];
      }
    }
#undef KSTEP
#undef STAGE
  }

  // ================= THIN 32x256 items (work-steal queue) =================
  int wmT   = wid & 1;                       // 2 wave rows of 16
  int t_row = (t >> 2) & 31;                 // A staging: row
  int t_off = (t >> 7) * 16 + (t & 3) * 4;   // A staging: byte col within 64B k-tile
  int addrAT = lk * 512 + (wmT * 16 + lrow) * 16;

  for (;;){
    if (t == 0) s_item = atomicAdd(&meta[10], 1);
    __syncthreads();
    int item = s_item;
    if (item >= nthin) break;
    int u = item >> 3, nb = item & 7;
    int e      = meta[144 + u];
    int m_base = meta[176 + u];
    int n0     = nb * BN;

    const char* agT = (const char*)xp + (size_t)(m_base + t_row) * (DIN * 2) + t_off;
    const char* bg0 = (const char*)Wt + (((size_t)e * DOUT + n0 + srow) * DIN + schk * 8) * 2;
    const char* bg1 = bg0 + (size_t)128 * DIN * 2;

#define STAGET(kt, BASE) do{ \
    gload4 (agT + (size_t)(kt) * 64, lds + (BASE) + t * 4); \
    gload16(bg0 + (size_t)(kt) * 64, lds + (BASE) + BOFF + ldst); \
    gload16(bg1 + (size_t)(kt) * 64, lds + (BASE) + BOFF + 8192 + ldst); \
  }while(0)

    fx4 accT[4];
#pragma unroll
    for (int n = 0; n < 4; ++n) accT[n] = (fx4){0.f, 0.f, 0.f, 0.f};

    float bcol[4];
#pragma unroll
    for (int n = 0; n < 4; ++n)
      bcol[n] = bias[(size_t)e * DOUT + n0 + wn * 64 + n * 16 + lrow];

#define KSTEPT(CB, SB, DOSTG, kt) do{ \
    sx8 af, bf[4]; \
    af = *(const sx8*)(lds + (CB) + addrAT); \
    _Pragma("unroll") for (int n = 0; n < 4; ++n) \
      bf[n] = *(const sx8*)(lds + (CB) + addrB + n * 1024); \
    if (DOSTG) STAGET((kt) + 2, SB); \
    __builtin_amdgcn_s_setprio(1); \
    _Pragma("unroll") for (int n = 0; n < 4; ++n) \
      accT[n] = __builtin_amdgcn_mfma_f32_16x16x32_bf16(af, bf[n], accT[n], 0, 0, 0); \
    __builtin_amdgcn_s_setprio(0); \
    if (DOSTG) asm volatile("s_waitcnt vmcnt(3)" ::: "memory"); \
    else       asm volatile("s_waitcnt vmcnt(0)" ::: "memory"); \
    __builtin_amdgcn_s_barrier(); \
    asm volatile("" ::: "memory"); \
  }while(0)

    STAGET(0, 0);
    STAGET(1, BUFSZ);
    asm volatile("s_waitcnt vmcnt(3)" ::: "memory");
    __builtin_amdgcn_s_barrier();
    asm volatile("" ::: "memory");

    for (int kt = 0; kt < 60; kt += 3){
      KSTEPT(0,         2*BUFSZ, 1, kt);
      KSTEPT(BUFSZ,     0,       1, kt + 1);
      KSTEPT(2*BUFSZ,   BUFSZ,   1, kt + 2);
    }
    KSTEPT(0,       2*BUFSZ, 1, 60);
    KSTEPT(BUFSZ,   0,       1, 61);
    KSTEPT(2*BUFSZ, 0,       0, 62);
    {
      sx8 af, bf[4];
      af = *(const sx8*)(lds + addrAT);
#pragma unroll
      for (int n = 0; n < 4; ++n) bf[n] = *(const sx8*)(lds + addrB + n * 1024);
#pragma unroll
      for (int n = 0; n < 4; ++n)
        accT[n] = __builtin_amdgcn_mfma_f32_16x16x32_bf16(af, bf[n], accT[n], 0, 0, 0);
    }

    {
      int rb = wmT * 16 + lk * 4;
      int prow[4];
#pragma unroll
      for (int q = 0; q < 4; ++q)
        prow[q] = perm[m_base + rb + q];
#pragma unroll
      for (int n = 0; n < 4; ++n){
        int col = n0 + wn * 64 + n * 16 + lrow;
        fx4 v = accT[n];
#pragma unroll
        for (int q = 0; q < 4; ++q)
          if (prow[q] >= 0)
            out[(size_t)prow[q] * DOUT + col] = v[q] + bcol[n];
      }
    }
#undef KSTEPT
#undef STAGET
  }
}

extern "C" void kernel_launch(void* const* d_in, const int* in_sizes, int n_in,
                              void* d_out, int out_size, void* d_ws, size_t ws_size,
                              hipStream_t stream) {
  const float* xs      = (const float*)d_in[0];
  const float* W       = (const float*)d_in[1];
  const float* b       = (const float*)d_in[2];
  const int*   mxs     = (const int*)d_in[3];
  const int*   actions = (const int*)d_in[4];
  float* out = (float*)d_out;

  int*   perm = (int*)d_ws;                                   // GROWS ints
  int*   meta = (int*)((char*)d_ws + 40960);
  short* Wt   = (short*)((char*)d_ws + 65536);                // 64 MB bf16 W^T
  short* xp   = (short*)((char*)d_ws + 65536 + (size_t)NEXP * DIN * DOUT * 2); // ~34.6 MB

  hipLaunchKernelGGL(k1_kernel, dim3(8193), dim3(256), 0, stream, W, Wt, actions, perm, meta);
  hipLaunchKernelGGL(prep_scatter, dim3(32), dim3(256), 0, stream, actions, mxs, perm, meta, out);
  hipLaunchKernelGGL(gatherx_kernel, dim3(GROWS), dim3(256), 0, stream, xs, perm, xp);
  hipLaunchKernelGGL(moe_gemm_kernel, dim3(512), dim3(512), 0, stream,
                     xp, Wt, b, perm, meta, out);
}